// Round 4
// baseline (763.543 us; speedup 1.0000x reference)
//
#include <hip/hip_runtime.h>

#define Bx 8
#define P0 20000
#define P1 5000
#define P2 1250
#define Mn 10
#define Wn 9
#define C0 3
#define C1 64
#define C2 128
#define KF 160000   // P2*C2
#define KCH 1280    // k_final chunk (125 chunks x 1280 = KF)

typedef float f32x4 __attribute__((ext_vector_type(4)));
typedef short bf16x8 __attribute__((ext_vector_type(8)));

__device__ __forceinline__ float elu_f(float x){ return x > 0.f ? x : expm1f(x); }

__device__ __forceinline__ unsigned short f2bf(float x){
    union { float f; unsigned u; } v; v.f = x;
    unsigned r = v.u + 0x7fffu + ((v.u >> 16) & 1u);   // RNE
    return (unsigned short)(r >> 16);
}
__device__ __forceinline__ float bf2f(unsigned short h){
    union { unsigned u; float f; } v; v.u = ((unsigned)h) << 16; return v.f;
}

// ---------------------------------------------------------------------------
// Pack weights2 (W, C2*C1) into MFMA B-fragment order, bf16:
// idx = ((s*8 + ot)*64 + lane)*8 + j  with o = ot*16 + (lane&15),
// k = s*32 + (lane>>4)*8 + j  (k = w*64 + i). One wave's B-frag = 1 KiB contiguous.
__global__ __launch_bounds__(256) void k_wpack(const float* __restrict__ w2,
                                               unsigned short* __restrict__ wT){
    int idx = blockIdx.x * 256 + threadIdx.x;          // < 73728 exactly
    int j  = idx & 7;
    int l  = (idx >> 3) & 63;
    int g  = idx >> 9;                                  // 0..143 = s*8+ot
    int ot = g & 7, s = g >> 3;
    int o  = ot * 16 + (l & 15);
    int k  = s * 32 + (l >> 4) * 8 + j;
    int w  = k >> 6, i = k & 63;
    wT[idx] = f2bf(w2[w * (C2 * C1) + o * C1 + i]);
}

// ---------------------------------------------------------------------------
// conv0 + ELU: h0[b,p,o] = elu(bias0[o] + sum_{k=w*3+i} wt0[k][o] * g[b][k])
// g[b][k] = sum_m w2[m][w] * x[b, nb0[p,m], i]
__global__ __launch_bounds__(256) void k_conv0(const float* __restrict__ x,
                                               const int* __restrict__ nb0,
                                               const float* __restrict__ weights0,
                                               const float* __restrict__ bias0,
                                               const float* __restrict__ w_weights0,
                                               float* __restrict__ h0){
    __shared__ int   s_nb[Mn];
    __shared__ float s_w2[Mn * Wn];
    __shared__ float s_xh[Bx * Mn * C0];
    __shared__ float s_g[Bx * 27];
    __shared__ float s_wt[27 * 64];
    int p = blockIdx.x, t = threadIdx.x;

    if (t < Mn) s_nb[t] = nb0[p * Mn + t];
    __syncthreads();
    if (t < Mn * Wn){
        int m = t / Wn;
        s_w2[t] = w_weights0[p * Mn * Wn + t] * (s_nb[m] != P0 ? 1.f : 0.f);
    }
    if (t < Bx * Mn * C0){
        int b = t / (Mn * C0), r = t % (Mn * C0), m = r / C0, i = r % C0;
        int idx = s_nb[m];
        s_xh[t] = (idx < P0) ? x[((size_t)b * P0 + idx) * C0 + i] : 0.f;
    }
    for (int e = t; e < 27 * 64; e += 256){
        int k = e >> 6, o = e & 63, w = k / 3, i = k - w * 3;
        s_wt[e] = weights0[w * (C1 * C0) + o * C0 + i];
    }
    __syncthreads();
    if (t < Bx * 27){
        int b = t / 27, k = t % 27, w = k / 3, i = k - w * 3;
        float a = 0.f;
        #pragma unroll
        for (int m = 0; m < Mn; ++m) a += s_w2[m * Wn + w] * s_xh[b * (Mn * C0) + m * C0 + i];
        s_g[t] = a;
    }
    __syncthreads();
    int b = t >> 5, o = (t & 31) * 2;
    float ax = bias0[o], ay = bias0[o + 1];
    #pragma unroll
    for (int k = 0; k < 27; ++k){
        float gv = s_g[b * 27 + k];
        ax += gv * s_wt[k * 64 + o];
        ay += gv * s_wt[k * 64 + o + 1];
    }
    float2 r; r.x = elu_f(ax); r.y = elu_f(ay);
    *(float2*)&h0[((size_t)b * P0 + p) * C1 + o] = r;
}

// ---------------------------------------------------------------------------
// pool over neighbors + ELU.  CIN channels, mask index = INPN.
__global__ __launch_bounds__(256) void k_pool1(const float* __restrict__ hin,
                                               const int* __restrict__ nb,
                                               const float* __restrict__ pnb,
                                               float* __restrict__ hout){
    __shared__ int   s_nb[Mn];
    __shared__ float s_pa[Mn];
    __shared__ float s_pw[Mn];
    int p = blockIdx.x, t = threadIdx.x;
    if (t < Mn){ s_nb[t] = nb[p * Mn + t]; s_pa[t] = pnb[p * Mn + t]; }
    __syncthreads();
    if (t < Mn){
        float denom = 1e-8f;
        for (int m = 0; m < Mn; ++m) denom += fabsf(s_pa[m]) * (s_nb[m] != P0 ? 1.f : 0.f);
        s_pw[t] = fabsf(s_pa[t]) * (s_nb[t] != P0 ? 1.f : 0.f) / denom;
    }
    __syncthreads();
    int b = t >> 5, c = (t & 31) * 2;
    float ax = 0.f, ay = 0.f;
    #pragma unroll
    for (int m = 0; m < Mn; ++m){
        int idx = s_nb[m];
        if (idx < P0){
            float wv = s_pw[m];
            const float2 v = *(const float2*)&hin[((size_t)b * P0 + idx) * C1 + c];
            ax += wv * v.x; ay += wv * v.y;
        }
    }
    float2 r; r.x = elu_f(ax); r.y = elu_f(ay);
    *(float2*)&hout[((size_t)b * P1 + p) * C1 + c] = r;
}

// ---------------------------------------------------------------------------
// conv2 + ELU via MFMA.  Block = 2 p1 x 8 b = 16 G-rows, K=576, N=128.
// Phase A: per-thread register gather builds G in LDS as bf16 hi+lo.
// Phase B: 4 waves x 2 o-tiles, 18 K-steps, A split (2 MFMA each), B plain bf16.
__global__ __launch_bounds__(256) void k_conv2(const float* __restrict__ h1,
                                               const int* __restrict__ nb2,
                                               const float* __restrict__ w_weights2,
                                               const float* __restrict__ bias2,
                                               const unsigned short* __restrict__ wT,
                                               float* __restrict__ h2){
    __shared__ int   s_nb[2][Mn];
    __shared__ float s_w2[2][Mn * Wn];
    __shared__ __align__(16) unsigned short s_gh[16 * 584];
    __shared__ __align__(16) unsigned short s_gl[16 * 584];
    int t = threadIdx.x;
    int p1b = blockIdx.x * 2;

    if (t < 2 * Mn){ int q = t / Mn, m = t % Mn; s_nb[q][m] = nb2[(p1b + q) * Mn + m]; }
    __syncthreads();
    if (t < 2 * Mn * Wn){
        int q = t / (Mn * Wn), r = t % (Mn * Wn), m = r / Wn;
        s_w2[q][r] = w_weights2[(size_t)(p1b + q) * Mn * Wn + r] * (s_nb[q][m] != P1 ? 1.f : 0.f);
    }
    __syncthreads();
    {   // Phase A: t -> (q, b, ig); g[w] is float4 over i = ig*4..ig*4+3
        int q = t >> 7, b = (t >> 4) & 7, ig = t & 15;
        float gx[Wn], gy[Wn], gz[Wn], gw[Wn];
        #pragma unroll
        for (int w = 0; w < Wn; ++w){ gx[w] = 0.f; gy[w] = 0.f; gz[w] = 0.f; gw[w] = 0.f; }
        #pragma unroll
        for (int m = 0; m < Mn; ++m){
            int idx = s_nb[q][m];
            if (idx < P1){
                const float4 v = *(const float4*)&h1[((size_t)b * P1 + idx) * C1 + ig * 4];
                #pragma unroll
                for (int w = 0; w < Wn; ++w){
                    float ww = s_w2[q][m * Wn + w];
                    gx[w] += ww * v.x; gy[w] += ww * v.y; gz[w] += ww * v.z; gw[w] += ww * v.w;
                }
            }
        }
        int r = q * 8 + b;
        #pragma unroll
        for (int w = 0; w < Wn; ++w){
            int base = r * 584 + w * 64 + ig * 4;
            ushort4 hh, ll;
            hh.x = f2bf(gx[w]); ll.x = f2bf(gx[w] - bf2f(hh.x));
            hh.y = f2bf(gy[w]); ll.y = f2bf(gy[w] - bf2f(hh.y));
            hh.z = f2bf(gz[w]); ll.z = f2bf(gz[w] - bf2f(hh.z));
            hh.w = f2bf(gw[w]); ll.w = f2bf(gw[w] - bf2f(hh.w));
            *(ushort4*)&s_gh[base] = hh;
            *(ushort4*)&s_gl[base] = ll;
        }
    }
    __syncthreads();
    {   // Phase B
        int wave = t >> 6, lane = t & 63;
        int n16 = lane & 15, quad = lane >> 4;
        f32x4 acc0 = {0.f, 0.f, 0.f, 0.f};
        f32x4 acc1 = {0.f, 0.f, 0.f, 0.f};
        const unsigned short* pAh = s_gh + n16 * 584 + quad * 8;   // A row = lane&15
        const unsigned short* pAl = s_gl + n16 * 584 + quad * 8;
        int ot0 = wave * 2, ot1 = ot0 + 1;
        const unsigned short* pB0 = wT + ot0 * 512 + lane * 8;
        const unsigned short* pB1 = wT + ot1 * 512 + lane * 8;
        #pragma unroll
        for (int s = 0; s < 18; ++s){
            bf16x8 ah = *(const bf16x8*)(pAh + s * 32);
            bf16x8 al = *(const bf16x8*)(pAl + s * 32);
            bf16x8 b0 = *(const bf16x8*)(pB0 + s * 4096);
            bf16x8 b1 = *(const bf16x8*)(pB1 + s * 4096);
            acc0 = __builtin_amdgcn_mfma_f32_16x16x32_bf16(al, b0, acc0, 0, 0, 0);
            acc0 = __builtin_amdgcn_mfma_f32_16x16x32_bf16(ah, b0, acc0, 0, 0, 0);
            acc1 = __builtin_amdgcn_mfma_f32_16x16x32_bf16(al, b1, acc1, 0, 0, 0);
            acc1 = __builtin_amdgcn_mfma_f32_16x16x32_bf16(ah, b1, acc1, 0, 0, 0);
        }
        int o0 = ot0 * 16 + n16, o1 = ot1 * 16 + n16;
        float bb0 = bias2[o0], bb1 = bias2[o1];
        #pragma unroll
        for (int reg = 0; reg < 4; ++reg){
            int r = quad * 4 + reg;           // D row = quad*4+reg
            int q = r >> 3, b = r & 7;
            size_t row = ((size_t)b * P1 + (p1b + q)) * C2;
            h2[row + o0] = elu_f(acc0[reg] + bb0);
            h2[row + o1] = elu_f(acc1[reg] + bb1);
        }
    }
}

// ---------------------------------------------------------------------------
// pool3 + ELU -> f (flattened h3)
__global__ __launch_bounds__(256) void k_pool3(const float* __restrict__ h2,
                                               const int* __restrict__ nb3,
                                               const float* __restrict__ pnb,
                                               float* __restrict__ f){
    __shared__ int   s_nb[Mn];
    __shared__ float s_pa[Mn];
    __shared__ float s_pw[Mn];
    int p = blockIdx.x, t = threadIdx.x;
    if (t < Mn){ s_nb[t] = nb3[p * Mn + t]; s_pa[t] = pnb[p * Mn + t]; }
    __syncthreads();
    if (t < Mn){
        float denom = 1e-8f;
        for (int m = 0; m < Mn; ++m) denom += fabsf(s_pa[m]) * (s_nb[m] != P1 ? 1.f : 0.f);
        s_pw[t] = fabsf(s_pa[t]) * (s_nb[t] != P1 ? 1.f : 0.f) / denom;
    }
    __syncthreads();
    int b = t >> 5, c = (t & 31) * 4;
    float ax = 0.f, ay = 0.f, az = 0.f, aw = 0.f;
    #pragma unroll
    for (int m = 0; m < Mn; ++m){
        int idx = s_nb[m];
        if (idx < P1){
            float wv = s_pw[m];
            const float4 v = *(const float4*)&h2[((size_t)b * P1 + idx) * C2 + c];
            ax += wv * v.x; ay += wv * v.y; az += wv * v.z; aw += wv * v.w;
        }
    }
    float4 r; r.x = elu_f(ax); r.y = elu_f(ay); r.z = elu_f(az); r.w = elu_f(aw);
    *(float4*)&f[(size_t)b * KF + (size_t)p * C2 + c] = r;
}

// ---------------------------------------------------------------------------
__global__ __launch_bounds__(256) void k_init_out(const float* __restrict__ b_miu,
                                                  const float* __restrict__ b_sigma,
                                                  float* __restrict__ out){
    int tid = blockIdx.x * 256 + threadIdx.x;
    if (tid < Bx * 512){
        int l = tid & 511;
        out[tid] = (l < 256) ? b_miu[l] : b_sigma[l - 256];
    }
}

// ---------------------------------------------------------------------------
// Final dense layer: out[b, l] += sum_k f[b,k] * Wrow[l][k].
// Redesigned for streaming: block = 8 waves = 8 l-rows x one 1280-k chunk.
// f chunk (8b x 1280k = 40 KB) staged in LDS, shared by all 8 waves.
// Per lane: acc[8] scalars (one per b), 5 independent coalesced float4 W-loads
// per chunk. VGPR ~56 -> 8 waves/SIMD; LDS 40KB x 4 blocks = 160KB -> 32
// waves/CU. W read exactly once from HBM. Grid = 64 lgroups x 125 kchunks.
__global__ __launch_bounds__(512) void k_final(const float* __restrict__ f,
                                               const float* __restrict__ Wm,
                                               const float* __restrict__ Ws,
                                               float* __restrict__ out){
    __shared__ __align__(16) float s_f[Bx * KCH];      // 40 KiB
    int t = threadIdx.x;
    int bx = blockIdx.x;
    int lg = bx / 125, kc = bx % 125;                  // 64 lgroups x 125 kchunks
    int k0 = kc * KCH;

    // stage f[b][k0 .. k0+KCH) -> LDS.  2560 float4s, 512 threads, 5 iters.
    #pragma unroll
    for (int it = 0; it < 5; ++it){
        int i = it * 512 + t;                          // < 2560
        int b = i / 320; int e = i - b * 320;
        *(float4*)&s_f[b * KCH + e * 4] =
            *(const float4*)&f[(size_t)b * KF + (size_t)(k0 + e * 4)];
    }
    __syncthreads();

    int wave = t >> 6, lane = t & 63;
    int l = lg * 8 + wave;                             // this wave's output row
    const float* Wrow = ((l < 256) ? (Wm + (size_t)l * KF)
                                   : (Ws + (size_t)(l - 256) * KF)) + k0;
    float acc[8];
    #pragma unroll
    for (int b = 0; b < 8; ++b) acc[b] = 0.f;

    #pragma unroll
    for (int it = 0; it < 5; ++it){
        int e = it * 64 + lane;                        // float4 index in chunk
        const float4 wv = *(const float4*)&Wrow[e * 4];
        #pragma unroll
        for (int b = 0; b < 8; ++b){
            const float4 fv = *(const float4*)&s_f[b * KCH + e * 4];
            acc[b] += wv.x * fv.x + wv.y * fv.y + wv.z * fv.z + wv.w * fv.w;
        }
    }

    #pragma unroll
    for (int b = 0; b < 8; ++b){
        float v = acc[b];
        v += __shfl_down(v, 32); v += __shfl_down(v, 16); v += __shfl_down(v, 8);
        v += __shfl_down(v, 4);  v += __shfl_down(v, 2);  v += __shfl_down(v, 1);
        if (lane == 0) atomicAdd(&out[b * 512 + l], v);
    }
}

// ---------------------------------------------------------------------------
extern "C" void kernel_launch(void* const* d_in, const int* in_sizes, int n_in,
                              void* d_out, int out_size, void* d_ws, size_t ws_size,
                              hipStream_t stream){
    const float* x            = (const float*)d_in[0];
    const int*   nb0          = (const int*)d_in[1];
    const int*   nb1          = (const int*)d_in[2];
    const int*   nb2          = (const int*)d_in[3];
    const int*   nb3          = (const int*)d_in[4];
    const float* weights0     = (const float*)d_in[5];
    const float* bias0        = (const float*)d_in[6];
    const float* w_weights0   = (const float*)d_in[7];
    const float* p_neighbors1 = (const float*)d_in[8];
    const float* weights2     = (const float*)d_in[9];
    const float* bias2        = (const float*)d_in[10];
    const float* w_weights2   = (const float*)d_in[11];
    const float* p_neighbors3 = (const float*)d_in[12];
    const float* W_miu        = (const float*)d_in[13];
    const float* b_miu        = (const float*)d_in[14];
    const float* W_sigma      = (const float*)d_in[15];
    const float* b_sigma      = (const float*)d_in[16];
    float* out = (float*)d_out;

    // ws layout (floats): h0 [0,10.24M) ; h1 [10.24M,12.8M) ; h2 reuses h0's
    // region [0,5.12M) after pool1 ; f [5.12M,6.4M) ; wT (bf16) at 12.8M.
    float* wsf = (float*)d_ws;
    float* h0 = wsf;
    float* h1 = wsf + 10240000;
    float* h2 = wsf;
    float* f  = wsf + 5120000;
    unsigned short* wT = (unsigned short*)(wsf + 12800000);

    k_wpack<<<288, 256, 0, stream>>>(weights2, wT);
    k_conv0<<<P0, 256, 0, stream>>>(x, nb0, weights0, bias0, w_weights0, h0);
    k_pool1<<<P1, 256, 0, stream>>>(h0, nb1, p_neighbors1, h1);
    k_conv2<<<P1 / 2, 256, 0, stream>>>(h1, nb2, w_weights2, bias2, wT, h2);
    k_pool3<<<P2, 256, 0, stream>>>(h2, nb3, p_neighbors3, f);
    k_init_out<<<16, 256, 0, stream>>>(b_miu, b_sigma, out);
    k_final<<<64 * 125, 512, 0, stream>>>(f, W_miu, W_sigma, out);
}

// Round 5
// 598.164 us; speedup vs baseline: 1.2765x; 1.2765x over previous
//
#include <hip/hip_runtime.h>

#define Bx 8
#define P0 20000
#define P1 5000
#define P2 1250
#define Mn 10
#define Wn 9
#define C0 3
#define C1 64
#define C2 128
#define KF 160000   // P2*C2
#define KCH 1280    // k_final chunk (125 chunks x 1280 = KF)

typedef float f32x4 __attribute__((ext_vector_type(4)));
typedef short bf16x8 __attribute__((ext_vector_type(8)));

__device__ __forceinline__ float elu_f(float x){ return x > 0.f ? x : expm1f(x); }

__device__ __forceinline__ unsigned short f2bf(float x){
    union { float f; unsigned u; } v; v.f = x;
    unsigned r = v.u + 0x7fffu + ((v.u >> 16) & 1u);   // RNE
    return (unsigned short)(r >> 16);
}
__device__ __forceinline__ float bf2f(unsigned short h){
    union { unsigned u; float f; } v; v.u = ((unsigned)h) << 16; return v.f;
}

// ---------------------------------------------------------------------------
// Pack weights2 (W, C2*C1) into MFMA B-fragment order, bf16:
// idx = ((s*8 + ot)*64 + lane)*8 + j  with o = ot*16 + (lane&15),
// k = s*32 + (lane>>4)*8 + j  (k = w*64 + i). One wave's B-frag = 1 KiB contiguous.
__global__ __launch_bounds__(256) void k_wpack(const float* __restrict__ w2,
                                               unsigned short* __restrict__ wT){
    int idx = blockIdx.x * 256 + threadIdx.x;          // < 73728 exactly
    int j  = idx & 7;
    int l  = (idx >> 3) & 63;
    int g  = idx >> 9;                                  // 0..143 = s*8+ot
    int ot = g & 7, s = g >> 3;
    int o  = ot * 16 + (l & 15);
    int k  = s * 32 + (l >> 4) * 8 + j;
    int w  = k >> 6, i = k & 63;
    wT[idx] = f2bf(w2[w * (C2 * C1) + o * C1 + i]);
}

// ---------------------------------------------------------------------------
// conv0 + ELU: h0[b,p,o] = elu(bias0[o] + sum_{k=w*3+i} wt0[k][o] * g[b][k])
// g[b][k] = sum_m w2[m][w] * x[b, nb0[p,m], i]
__global__ __launch_bounds__(256) void k_conv0(const float* __restrict__ x,
                                               const int* __restrict__ nb0,
                                               const float* __restrict__ weights0,
                                               const float* __restrict__ bias0,
                                               const float* __restrict__ w_weights0,
                                               float* __restrict__ h0){
    __shared__ int   s_nb[Mn];
    __shared__ float s_w2[Mn * Wn];
    __shared__ float s_xh[Bx * Mn * C0];
    __shared__ float s_g[Bx * 27];
    __shared__ float s_wt[27 * 64];
    int p = blockIdx.x, t = threadIdx.x;

    if (t < Mn) s_nb[t] = nb0[p * Mn + t];
    __syncthreads();
    if (t < Mn * Wn){
        int m = t / Wn;
        s_w2[t] = w_weights0[p * Mn * Wn + t] * (s_nb[m] != P0 ? 1.f : 0.f);
    }
    if (t < Bx * Mn * C0){
        int b = t / (Mn * C0), r = t % (Mn * C0), m = r / C0, i = r % C0;
        int idx = s_nb[m];
        s_xh[t] = (idx < P0) ? x[((size_t)b * P0 + idx) * C0 + i] : 0.f;
    }
    for (int e = t; e < 27 * 64; e += 256){
        int k = e >> 6, o = e & 63, w = k / 3, i = k - w * 3;
        s_wt[e] = weights0[w * (C1 * C0) + o * C0 + i];
    }
    __syncthreads();
    if (t < Bx * 27){
        int b = t / 27, k = t % 27, w = k / 3, i = k - w * 3;
        float a = 0.f;
        #pragma unroll
        for (int m = 0; m < Mn; ++m) a += s_w2[m * Wn + w] * s_xh[b * (Mn * C0) + m * C0 + i];
        s_g[t] = a;
    }
    __syncthreads();
    int b = t >> 5, o = (t & 31) * 2;
    float ax = bias0[o], ay = bias0[o + 1];
    #pragma unroll
    for (int k = 0; k < 27; ++k){
        float gv = s_g[b * 27 + k];
        ax += gv * s_wt[k * 64 + o];
        ay += gv * s_wt[k * 64 + o + 1];
    }
    float2 r; r.x = elu_f(ax); r.y = elu_f(ay);
    *(float2*)&h0[((size_t)b * P0 + p) * C1 + o] = r;
}

// ---------------------------------------------------------------------------
// pool over neighbors + ELU.  CIN channels, mask index = INPN.
__global__ __launch_bounds__(256) void k_pool1(const float* __restrict__ hin,
                                               const int* __restrict__ nb,
                                               const float* __restrict__ pnb,
                                               float* __restrict__ hout){
    __shared__ int   s_nb[Mn];
    __shared__ float s_pa[Mn];
    __shared__ float s_pw[Mn];
    int p = blockIdx.x, t = threadIdx.x;
    if (t < Mn){ s_nb[t] = nb[p * Mn + t]; s_pa[t] = pnb[p * Mn + t]; }
    __syncthreads();
    if (t < Mn){
        float denom = 1e-8f;
        for (int m = 0; m < Mn; ++m) denom += fabsf(s_pa[m]) * (s_nb[m] != P0 ? 1.f : 0.f);
        s_pw[t] = fabsf(s_pa[t]) * (s_nb[t] != P0 ? 1.f : 0.f) / denom;
    }
    __syncthreads();
    int b = t >> 5, c = (t & 31) * 2;
    float ax = 0.f, ay = 0.f;
    #pragma unroll
    for (int m = 0; m < Mn; ++m){
        int idx = s_nb[m];
        if (idx < P0){
            float wv = s_pw[m];
            const float2 v = *(const float2*)&hin[((size_t)b * P0 + idx) * C1 + c];
            ax += wv * v.x; ay += wv * v.y;
        }
    }
    float2 r; r.x = elu_f(ax); r.y = elu_f(ay);
    *(float2*)&hout[((size_t)b * P1 + p) * C1 + c] = r;
}

// ---------------------------------------------------------------------------
// conv2 + ELU via MFMA.  Block = 2 p1 x 8 b = 16 G-rows, K=576, N=128.
// Phase A: per-thread register gather builds G in LDS as bf16 hi+lo.
// Phase B: 4 waves x 2 o-tiles, 18 K-steps, A split (2 MFMA each), B plain bf16.
__global__ __launch_bounds__(256) void k_conv2(const float* __restrict__ h1,
                                               const int* __restrict__ nb2,
                                               const float* __restrict__ w_weights2,
                                               const float* __restrict__ bias2,
                                               const unsigned short* __restrict__ wT,
                                               float* __restrict__ h2){
    __shared__ int   s_nb[2][Mn];
    __shared__ float s_w2[2][Mn * Wn];
    __shared__ __align__(16) unsigned short s_gh[16 * 584];
    __shared__ __align__(16) unsigned short s_gl[16 * 584];
    int t = threadIdx.x;
    int p1b = blockIdx.x * 2;

    if (t < 2 * Mn){ int q = t / Mn, m = t % Mn; s_nb[q][m] = nb2[(p1b + q) * Mn + m]; }
    __syncthreads();
    if (t < 2 * Mn * Wn){
        int q = t / (Mn * Wn), r = t % (Mn * Wn), m = r / Wn;
        s_w2[q][r] = w_weights2[(size_t)(p1b + q) * Mn * Wn + r] * (s_nb[q][m] != P1 ? 1.f : 0.f);
    }
    __syncthreads();
    {   // Phase A: t -> (q, b, ig); g[w] is float4 over i = ig*4..ig*4+3
        int q = t >> 7, b = (t >> 4) & 7, ig = t & 15;
        float gx[Wn], gy[Wn], gz[Wn], gw[Wn];
        #pragma unroll
        for (int w = 0; w < Wn; ++w){ gx[w] = 0.f; gy[w] = 0.f; gz[w] = 0.f; gw[w] = 0.f; }
        #pragma unroll
        for (int m = 0; m < Mn; ++m){
            int idx = s_nb[q][m];
            if (idx < P1){
                const float4 v = *(const float4*)&h1[((size_t)b * P1 + idx) * C1 + ig * 4];
                #pragma unroll
                for (int w = 0; w < Wn; ++w){
                    float ww = s_w2[q][m * Wn + w];
                    gx[w] += ww * v.x; gy[w] += ww * v.y; gz[w] += ww * v.z; gw[w] += ww * v.w;
                }
            }
        }
        int r = q * 8 + b;
        #pragma unroll
        for (int w = 0; w < Wn; ++w){
            int base = r * 584 + w * 64 + ig * 4;
            ushort4 hh, ll;
            hh.x = f2bf(gx[w]); ll.x = f2bf(gx[w] - bf2f(hh.x));
            hh.y = f2bf(gy[w]); ll.y = f2bf(gy[w] - bf2f(hh.y));
            hh.z = f2bf(gz[w]); ll.z = f2bf(gz[w] - bf2f(hh.z));
            hh.w = f2bf(gw[w]); ll.w = f2bf(gw[w] - bf2f(hh.w));
            *(ushort4*)&s_gh[base] = hh;
            *(ushort4*)&s_gl[base] = ll;
        }
    }
    __syncthreads();
    {   // Phase B
        int wave = t >> 6, lane = t & 63;
        int n16 = lane & 15, quad = lane >> 4;
        f32x4 acc0 = {0.f, 0.f, 0.f, 0.f};
        f32x4 acc1 = {0.f, 0.f, 0.f, 0.f};
        const unsigned short* pAh = s_gh + n16 * 584 + quad * 8;   // A row = lane&15
        const unsigned short* pAl = s_gl + n16 * 584 + quad * 8;
        int ot0 = wave * 2, ot1 = ot0 + 1;
        const unsigned short* pB0 = wT + ot0 * 512 + lane * 8;
        const unsigned short* pB1 = wT + ot1 * 512 + lane * 8;
        #pragma unroll
        for (int s = 0; s < 18; ++s){
            bf16x8 ah = *(const bf16x8*)(pAh + s * 32);
            bf16x8 al = *(const bf16x8*)(pAl + s * 32);
            bf16x8 b0 = *(const bf16x8*)(pB0 + s * 4096);
            bf16x8 b1 = *(const bf16x8*)(pB1 + s * 4096);
            acc0 = __builtin_amdgcn_mfma_f32_16x16x32_bf16(al, b0, acc0, 0, 0, 0);
            acc0 = __builtin_amdgcn_mfma_f32_16x16x32_bf16(ah, b0, acc0, 0, 0, 0);
            acc1 = __builtin_amdgcn_mfma_f32_16x16x32_bf16(al, b1, acc1, 0, 0, 0);
            acc1 = __builtin_amdgcn_mfma_f32_16x16x32_bf16(ah, b1, acc1, 0, 0, 0);
        }
        int o0 = ot0 * 16 + n16, o1 = ot1 * 16 + n16;
        float bb0 = bias2[o0], bb1 = bias2[o1];
        #pragma unroll
        for (int reg = 0; reg < 4; ++reg){
            int r = quad * 4 + reg;           // D row = quad*4+reg
            int q = r >> 3, b = r & 7;
            size_t row = ((size_t)b * P1 + (p1b + q)) * C2;
            h2[row + o0] = elu_f(acc0[reg] + bb0);
            h2[row + o1] = elu_f(acc1[reg] + bb1);
        }
    }
}

// ---------------------------------------------------------------------------
// pool3 + ELU -> f (flattened h3)
__global__ __launch_bounds__(256) void k_pool3(const float* __restrict__ h2,
                                               const int* __restrict__ nb3,
                                               const float* __restrict__ pnb,
                                               float* __restrict__ f){
    __shared__ int   s_nb[Mn];
    __shared__ float s_pa[Mn];
    __shared__ float s_pw[Mn];
    int p = blockIdx.x, t = threadIdx.x;
    if (t < Mn){ s_nb[t] = nb3[p * Mn + t]; s_pa[t] = pnb[p * Mn + t]; }
    __syncthreads();
    if (t < Mn){
        float denom = 1e-8f;
        for (int m = 0; m < Mn; ++m) denom += fabsf(s_pa[m]) * (s_nb[m] != P1 ? 1.f : 0.f);
        s_pw[t] = fabsf(s_pa[t]) * (s_nb[t] != P1 ? 1.f : 0.f) / denom;
    }
    __syncthreads();
    int b = t >> 5, c = (t & 31) * 4;
    float ax = 0.f, ay = 0.f, az = 0.f, aw = 0.f;
    #pragma unroll
    for (int m = 0; m < Mn; ++m){
        int idx = s_nb[m];
        if (idx < P1){
            float wv = s_pw[m];
            const float4 v = *(const float4*)&h2[((size_t)b * P1 + idx) * C2 + c];
            ax += wv * v.x; ay += wv * v.y; az += wv * v.z; aw += wv * v.w;
        }
    }
    float4 r; r.x = elu_f(ax); r.y = elu_f(ay); r.z = elu_f(az); r.w = elu_f(aw);
    *(float4*)&f[(size_t)b * KF + (size_t)p * C2 + c] = r;
}

// ---------------------------------------------------------------------------
__global__ __launch_bounds__(256) void k_init_out(const float* __restrict__ b_miu,
                                                  const float* __restrict__ b_sigma,
                                                  float* __restrict__ out){
    int tid = blockIdx.x * 256 + threadIdx.x;
    if (tid < Bx * 512){
        int l = tid & 511;
        out[tid] = (l < 256) ? b_miu[l] : b_sigma[l - 256];
    }
}

// ---------------------------------------------------------------------------
// Final dense layer: out[b, l] += sum_k f[b,k] * Wrow[l][k].
// v3: W-stream-dominant blocks. Block = 512 thr (8 waves), one 1280-k chunk.
// f chunk (40 KB) staged once; each wave then processes TWO (miu,sigma)
// row-PAIRS sequentially (lp = lpg*16 + wave*2 + s), acc[16] per pass, so
// the block consumes 160 KB of W per 40 KB staged (4:1) with one barrier.
// LDS 40KB -> 4 blocks/CU -> 32 waves/CU if VGPR<=64 (acc16+wv8+addr ~56).
// Per wave-pass: 10 independent coalesced float4 W-loads in flight.
// Grid = 125 kchunks x 16 lpgroups = 2000 blocks.
__global__ __launch_bounds__(512) void k_final(const float* __restrict__ f,
                                               const float* __restrict__ Wm,
                                               const float* __restrict__ Ws,
                                               float* __restrict__ out){
    __shared__ __align__(16) float s_f[Bx * KCH];      // 40 KiB
    int t = threadIdx.x;
    int bx = blockIdx.x;
    int kc = bx % 125, lpg = bx / 125;                 // 125 kchunks x 16 lpgroups
    int k0 = kc * KCH;

    // stage f[b][k0 .. k0+KCH) -> LDS.  2560 float4s, 512 threads, 5 iters.
    #pragma unroll
    for (int it = 0; it < 5; ++it){
        int i = it * 512 + t;                          // < 2560
        int b = i / 320, e = i - b * 320;
        *(float4*)&s_f[b * KCH + e * 4] =
            *(const float4*)&f[(size_t)b * KF + (size_t)(k0 + e * 4)];
    }
    __syncthreads();

    int wave = t >> 6, lane = t & 63;
    #pragma unroll
    for (int s = 0; s < 2; ++s){
        int lp = lpg * 16 + wave * 2 + s;              // [0,256): row of Wm AND Ws
        const float* Wrm = Wm + (size_t)lp * KF + k0;
        const float* Wrs = Ws + (size_t)lp * KF + k0;
        float am[8], asg[8];
        #pragma unroll
        for (int b = 0; b < 8; ++b){ am[b] = 0.f; asg[b] = 0.f; }
        #pragma unroll
        for (int it = 0; it < 5; ++it){
            int e = it * 64 + lane;                    // float4 index in chunk
            const float4 wm = *(const float4*)&Wrm[e * 4];
            const float4 ws = *(const float4*)&Wrs[e * 4];
            #pragma unroll
            for (int b = 0; b < 8; ++b){
                const float4 fv = *(const float4*)&s_f[b * KCH + e * 4];
                am[b]  += wm.x * fv.x + wm.y * fv.y + wm.z * fv.z + wm.w * fv.w;
                asg[b] += ws.x * fv.x + ws.y * fv.y + ws.z * fv.z + ws.w * fv.w;
            }
        }
        #pragma unroll
        for (int b = 0; b < 8; ++b){
            float vm = am[b], vs = asg[b];
            vm += __shfl_down(vm, 32); vm += __shfl_down(vm, 16); vm += __shfl_down(vm, 8);
            vm += __shfl_down(vm, 4);  vm += __shfl_down(vm, 2);  vm += __shfl_down(vm, 1);
            vs += __shfl_down(vs, 32); vs += __shfl_down(vs, 16); vs += __shfl_down(vs, 8);
            vs += __shfl_down(vs, 4);  vs += __shfl_down(vs, 2);  vs += __shfl_down(vs, 1);
            if (lane == 0){
                atomicAdd(&out[b * 512 + lp], vm);           // miu (l = lp)
                atomicAdd(&out[b * 512 + 256 + lp], vs);     // sigma (l = 256+lp)
            }
        }
    }
}

// ---------------------------------------------------------------------------
extern "C" void kernel_launch(void* const* d_in, const int* in_sizes, int n_in,
                              void* d_out, int out_size, void* d_ws, size_t ws_size,
                              hipStream_t stream){
    const float* x            = (const float*)d_in[0];
    const int*   nb0          = (const int*)d_in[1];
    const int*   nb1          = (const int*)d_in[2];
    const int*   nb2          = (const int*)d_in[3];
    const int*   nb3          = (const int*)d_in[4];
    const float* weights0     = (const float*)d_in[5];
    const float* bias0        = (const float*)d_in[6];
    const float* w_weights0   = (const float*)d_in[7];
    const float* p_neighbors1 = (const float*)d_in[8];
    const float* weights2     = (const float*)d_in[9];
    const float* bias2        = (const float*)d_in[10];
    const float* w_weights2   = (const float*)d_in[11];
    const float* p_neighbors3 = (const float*)d_in[12];
    const float* W_miu        = (const float*)d_in[13];
    const float* b_miu        = (const float*)d_in[14];
    const float* W_sigma      = (const float*)d_in[15];
    const float* b_sigma      = (const float*)d_in[16];
    float* out = (float*)d_out;

    // ws layout (floats): h0 [0,10.24M) ; h1 [10.24M,12.8M) ; h2 reuses h0's
    // region [0,5.12M) after pool1 ; f [5.12M,6.4M) ; wT (bf16) at 12.8M.
    float* wsf = (float*)d_ws;
    float* h0 = wsf;
    float* h1 = wsf + 10240000;
    float* h2 = wsf;
    float* f  = wsf + 5120000;
    unsigned short* wT = (unsigned short*)(wsf + 12800000);

    k_wpack<<<288, 256, 0, stream>>>(weights2, wT);
    k_conv0<<<P0, 256, 0, stream>>>(x, nb0, weights0, bias0, w_weights0, h0);
    k_pool1<<<P1, 256, 0, stream>>>(h0, nb1, p_neighbors1, h1);
    k_conv2<<<P1 / 2, 256, 0, stream>>>(h1, nb2, w_weights2, bias2, wT, h2);
    k_pool3<<<P2, 256, 0, stream>>>(h2, nb3, p_neighbors3, f);
    k_init_out<<<16, 256, 0, stream>>>(b_miu, b_sigma, out);
    k_final<<<125 * 16, 512, 0, stream>>>(f, W_miu, W_sigma, out);
}

// Round 6
// 518.451 us; speedup vs baseline: 1.4727x; 1.1538x over previous
//
#include <hip/hip_runtime.h>

#define Bx 8
#define P0 20000
#define P1 5000
#define P2 1250
#define Mn 10
#define Wn 9
#define C0 3
#define C1 64
#define C2 128
#define KF 160000   // P2*C2
#define KCH 640     // k_final chunk (250 chunks x 640 = KF)

typedef float f32x4 __attribute__((ext_vector_type(4)));
typedef short bf16x8 __attribute__((ext_vector_type(8)));

__device__ __forceinline__ float elu_f(float x){ return x > 0.f ? x : expm1f(x); }

__device__ __forceinline__ unsigned short f2bf(float x){
    union { float f; unsigned u; } v; v.f = x;
    unsigned r = v.u + 0x7fffu + ((v.u >> 16) & 1u);   // RNE
    return (unsigned short)(r >> 16);
}
__device__ __forceinline__ float bf2f(unsigned short h){
    union { unsigned u; float f; } v; v.u = ((unsigned)h) << 16; return v.f;
}

// ---------------------------------------------------------------------------
// Pack weights2 (W, C2*C1) into MFMA B-fragment order, bf16:
// idx = ((s*8 + ot)*64 + lane)*8 + j  with o = ot*16 + (lane&15),
// k = s*32 + (lane>>4)*8 + j  (k = w*64 + i). One wave's B-frag = 1 KiB contiguous.
__global__ __launch_bounds__(256) void k_wpack(const float* __restrict__ w2,
                                               unsigned short* __restrict__ wT){
    int idx = blockIdx.x * 256 + threadIdx.x;          // < 73728 exactly
    int j  = idx & 7;
    int l  = (idx >> 3) & 63;
    int g  = idx >> 9;                                  // 0..143 = s*8+ot
    int ot = g & 7, s = g >> 3;
    int o  = ot * 16 + (l & 15);
    int k  = s * 32 + (l >> 4) * 8 + j;
    int w  = k >> 6, i = k & 63;
    wT[idx] = f2bf(w2[w * (C2 * C1) + o * C1 + i]);
}

// ---------------------------------------------------------------------------
// conv0 + ELU: h0[b,p,o] = elu(bias0[o] + sum_{k=w*3+i} wt0[k][o] * g[b][k])
// g[b][k] = sum_m w2[m][w] * x[b, nb0[p,m], i]
__global__ __launch_bounds__(256) void k_conv0(const float* __restrict__ x,
                                               const int* __restrict__ nb0,
                                               const float* __restrict__ weights0,
                                               const float* __restrict__ bias0,
                                               const float* __restrict__ w_weights0,
                                               float* __restrict__ h0){
    __shared__ int   s_nb[Mn];
    __shared__ float s_w2[Mn * Wn];
    __shared__ float s_xh[Bx * Mn * C0];
    __shared__ float s_g[Bx * 27];
    __shared__ float s_wt[27 * 64];
    int p = blockIdx.x, t = threadIdx.x;

    if (t < Mn) s_nb[t] = nb0[p * Mn + t];
    __syncthreads();
    if (t < Mn * Wn){
        int m = t / Wn;
        s_w2[t] = w_weights0[p * Mn * Wn + t] * (s_nb[m] != P0 ? 1.f : 0.f);
    }
    if (t < Bx * Mn * C0){
        int b = t / (Mn * C0), r = t % (Mn * C0), m = r / C0, i = r % C0;
        int idx = s_nb[m];
        s_xh[t] = (idx < P0) ? x[((size_t)b * P0 + idx) * C0 + i] : 0.f;
    }
    for (int e = t; e < 27 * 64; e += 256){
        int k = e >> 6, o = e & 63, w = k / 3, i = k - w * 3;
        s_wt[e] = weights0[w * (C1 * C0) + o * C0 + i];
    }
    __syncthreads();
    if (t < Bx * 27){
        int b = t / 27, k = t % 27, w = k / 3, i = k - w * 3;
        float a = 0.f;
        #pragma unroll
        for (int m = 0; m < Mn; ++m) a += s_w2[m * Wn + w] * s_xh[b * (Mn * C0) + m * C0 + i];
        s_g[t] = a;
    }
    __syncthreads();
    int b = t >> 5, o = (t & 31) * 2;
    float ax = bias0[o], ay = bias0[o + 1];
    #pragma unroll
    for (int k = 0; k < 27; ++k){
        float gv = s_g[b * 27 + k];
        ax += gv * s_wt[k * 64 + o];
        ay += gv * s_wt[k * 64 + o + 1];
    }
    float2 r; r.x = elu_f(ax); r.y = elu_f(ay);
    *(float2*)&h0[((size_t)b * P0 + p) * C1 + o] = r;
}

// ---------------------------------------------------------------------------
// pool over neighbors + ELU.  CIN channels, mask index = INPN.
__global__ __launch_bounds__(256) void k_pool1(const float* __restrict__ hin,
                                               const int* __restrict__ nb,
                                               const float* __restrict__ pnb,
                                               float* __restrict__ hout){
    __shared__ int   s_nb[Mn];
    __shared__ float s_pa[Mn];
    __shared__ float s_pw[Mn];
    int p = blockIdx.x, t = threadIdx.x;
    if (t < Mn){ s_nb[t] = nb[p * Mn + t]; s_pa[t] = pnb[p * Mn + t]; }
    __syncthreads();
    if (t < Mn){
        float denom = 1e-8f;
        for (int m = 0; m < Mn; ++m) denom += fabsf(s_pa[m]) * (s_nb[m] != P0 ? 1.f : 0.f);
        s_pw[t] = fabsf(s_pa[t]) * (s_nb[t] != P0 ? 1.f : 0.f) / denom;
    }
    __syncthreads();
    int b = t >> 5, c = (t & 31) * 2;
    float ax = 0.f, ay = 0.f;
    #pragma unroll
    for (int m = 0; m < Mn; ++m){
        int idx = s_nb[m];
        if (idx < P0){
            float wv = s_pw[m];
            const float2 v = *(const float2*)&hin[((size_t)b * P0 + idx) * C1 + c];
            ax += wv * v.x; ay += wv * v.y;
        }
    }
    float2 r; r.x = elu_f(ax); r.y = elu_f(ay);
    *(float2*)&hout[((size_t)b * P1 + p) * C1 + c] = r;
}

// ---------------------------------------------------------------------------
// conv2 + ELU via MFMA.  Block = 2 p1 x 8 b = 16 G-rows, K=576, N=128.
// Phase A: per-thread register gather builds G in LDS as bf16 hi+lo.
// Phase B: 4 waves x 2 o-tiles, 18 K-steps, A split (2 MFMA each), B plain bf16.
__global__ __launch_bounds__(256) void k_conv2(const float* __restrict__ h1,
                                               const int* __restrict__ nb2,
                                               const float* __restrict__ w_weights2,
                                               const float* __restrict__ bias2,
                                               const unsigned short* __restrict__ wT,
                                               float* __restrict__ h2){
    __shared__ int   s_nb[2][Mn];
    __shared__ float s_w2[2][Mn * Wn];
    __shared__ __align__(16) unsigned short s_gh[16 * 584];
    __shared__ __align__(16) unsigned short s_gl[16 * 584];
    int t = threadIdx.x;
    int p1b = blockIdx.x * 2;

    if (t < 2 * Mn){ int q = t / Mn, m = t % Mn; s_nb[q][m] = nb2[(p1b + q) * Mn + m]; }
    __syncthreads();
    if (t < 2 * Mn * Wn){
        int q = t / (Mn * Wn), r = t % (Mn * Wn), m = r / Wn;
        s_w2[q][r] = w_weights2[(size_t)(p1b + q) * Mn * Wn + r] * (s_nb[q][m] != P1 ? 1.f : 0.f);
    }
    __syncthreads();
    {   // Phase A: t -> (q, b, ig); g[w] is float4 over i = ig*4..ig*4+3
        int q = t >> 7, b = (t >> 4) & 7, ig = t & 15;
        float gx[Wn], gy[Wn], gz[Wn], gw[Wn];
        #pragma unroll
        for (int w = 0; w < Wn; ++w){ gx[w] = 0.f; gy[w] = 0.f; gz[w] = 0.f; gw[w] = 0.f; }
        #pragma unroll
        for (int m = 0; m < Mn; ++m){
            int idx = s_nb[q][m];
            if (idx < P1){
                const float4 v = *(const float4*)&h1[((size_t)b * P1 + idx) * C1 + ig * 4];
                #pragma unroll
                for (int w = 0; w < Wn; ++w){
                    float ww = s_w2[q][m * Wn + w];
                    gx[w] += ww * v.x; gy[w] += ww * v.y; gz[w] += ww * v.z; gw[w] += ww * v.w;
                }
            }
        }
        int r = q * 8 + b;
        #pragma unroll
        for (int w = 0; w < Wn; ++w){
            int base = r * 584 + w * 64 + ig * 4;
            ushort4 hh, ll;
            hh.x = f2bf(gx[w]); ll.x = f2bf(gx[w] - bf2f(hh.x));
            hh.y = f2bf(gy[w]); ll.y = f2bf(gy[w] - bf2f(hh.y));
            hh.z = f2bf(gz[w]); ll.z = f2bf(gz[w] - bf2f(hh.z));
            hh.w = f2bf(gw[w]); ll.w = f2bf(gw[w] - bf2f(hh.w));
            *(ushort4*)&s_gh[base] = hh;
            *(ushort4*)&s_gl[base] = ll;
        }
    }
    __syncthreads();
    {   // Phase B
        int wave = t >> 6, lane = t & 63;
        int n16 = lane & 15, quad = lane >> 4;
        f32x4 acc0 = {0.f, 0.f, 0.f, 0.f};
        f32x4 acc1 = {0.f, 0.f, 0.f, 0.f};
        const unsigned short* pAh = s_gh + n16 * 584 + quad * 8;   // A row = lane&15
        const unsigned short* pAl = s_gl + n16 * 584 + quad * 8;
        int ot0 = wave * 2, ot1 = ot0 + 1;
        const unsigned short* pB0 = wT + ot0 * 512 + lane * 8;
        const unsigned short* pB1 = wT + ot1 * 512 + lane * 8;
        #pragma unroll
        for (int s = 0; s < 18; ++s){
            bf16x8 ah = *(const bf16x8*)(pAh + s * 32);
            bf16x8 al = *(const bf16x8*)(pAl + s * 32);
            bf16x8 b0 = *(const bf16x8*)(pB0 + s * 4096);
            bf16x8 b1 = *(const bf16x8*)(pB1 + s * 4096);
            acc0 = __builtin_amdgcn_mfma_f32_16x16x32_bf16(al, b0, acc0, 0, 0, 0);
            acc0 = __builtin_amdgcn_mfma_f32_16x16x32_bf16(ah, b0, acc0, 0, 0, 0);
            acc1 = __builtin_amdgcn_mfma_f32_16x16x32_bf16(al, b1, acc1, 0, 0, 0);
            acc1 = __builtin_amdgcn_mfma_f32_16x16x32_bf16(ah, b1, acc1, 0, 0, 0);
        }
        int o0 = ot0 * 16 + n16, o1 = ot1 * 16 + n16;
        float bb0 = bias2[o0], bb1 = bias2[o1];
        #pragma unroll
        for (int reg = 0; reg < 4; ++reg){
            int r = quad * 4 + reg;           // D row = quad*4+reg
            int q = r >> 3, b = r & 7;
            size_t row = ((size_t)b * P1 + (p1b + q)) * C2;
            h2[row + o0] = elu_f(acc0[reg] + bb0);
            h2[row + o1] = elu_f(acc1[reg] + bb1);
        }
    }
}

// ---------------------------------------------------------------------------
// pool3 + ELU -> f (flattened h3)
__global__ __launch_bounds__(256) void k_pool3(const float* __restrict__ h2,
                                               const int* __restrict__ nb3,
                                               const float* __restrict__ pnb,
                                               float* __restrict__ f){
    __shared__ int   s_nb[Mn];
    __shared__ float s_pa[Mn];
    __shared__ float s_pw[Mn];
    int p = blockIdx.x, t = threadIdx.x;
    if (t < Mn){ s_nb[t] = nb3[p * Mn + t]; s_pa[t] = pnb[p * Mn + t]; }
    __syncthreads();
    if (t < Mn){
        float denom = 1e-8f;
        for (int m = 0; m < Mn; ++m) denom += fabsf(s_pa[m]) * (s_nb[m] != P1 ? 1.f : 0.f);
        s_pw[t] = fabsf(s_pa[t]) * (s_nb[t] != P1 ? 1.f : 0.f) / denom;
    }
    __syncthreads();
    int b = t >> 5, c = (t & 31) * 4;
    float ax = 0.f, ay = 0.f, az = 0.f, aw = 0.f;
    #pragma unroll
    for (int m = 0; m < Mn; ++m){
        int idx = s_nb[m];
        if (idx < P1){
            float wv = s_pw[m];
            const float4 v = *(const float4*)&h2[((size_t)b * P1 + idx) * C2 + c];
            ax += wv * v.x; ay += wv * v.y; az += wv * v.z; aw += wv * v.w;
        }
    }
    float4 r; r.x = elu_f(ax); r.y = elu_f(ay); r.z = elu_f(az); r.w = elu_f(aw);
    *(float4*)&f[(size_t)b * KF + (size_t)p * C2 + c] = r;
}

// ---------------------------------------------------------------------------
__global__ __launch_bounds__(256) void k_init_out(const float* __restrict__ b_miu,
                                                  const float* __restrict__ b_sigma,
                                                  float* __restrict__ out){
    int tid = blockIdx.x * 256 + threadIdx.x;
    if (tid < Bx * 512){
        int l = tid & 511;
        out[tid] = (l < 256) ? b_miu[l] : b_sigma[l - 256];
    }
}

// ---------------------------------------------------------------------------
// Final dense layer: out[b, l] += sum_k f[b,k] * Wrow[l][k].
// v4: one-shot LDS-staged streaming. Block = 256 thr, owns 8 W-rows x one
// 640-k chunk. Stage W-chunk (20 KB) + f-chunk (20 KB) into LDS with 10
// back-to-back float4 loads/thread (in-flight bytes live in the memory
// system, not VGPRs -> MLP no longer gated by register file). One barrier,
// then register-blocked LDS compute: thread = (4l x 2b) tile x 32-lane
// k-slice, acc[8] scalars. LDS 40 KB -> 4 blocks/CU; VGPR ~55 target.
// W read exactly once from HBM; f chunk shared by 64 consecutive blocks
// (kc-major grid) -> L2/L3. Grid = 250 kchunks x 64 lgroups = 16000.
__global__ __launch_bounds__(256) void k_final(const float* __restrict__ f,
                                               const float* __restrict__ Wm,
                                               const float* __restrict__ Ws,
                                               float* __restrict__ out){
    __shared__ __align__(16) float s_w[8 * KCH];       // 20 KiB
    __shared__ __align__(16) float s_f[Bx * KCH];      // 20 KiB
    int t = threadIdx.x;
    int bx = blockIdx.x;
    int lg = bx & 63, kc = bx >> 6;                    // consecutive bx share kc
    int k0 = kc * KCH;

    // lg < 32 -> rows lg*8..+8 all in Wm; else all in Ws.
    const float* Wsrc = (lg < 32) ? Wm : Ws;
    int lbase = (lg & 31) * 8;
    int oofs  = ((lg < 32) ? 0 : 256) + lbase;         // out column base

    // Stage: W 1280 float4s + f 1280 float4s, 256 threads, 5+5 iters.
    #pragma unroll
    for (int it = 0; it < 5; ++it){
        int i = it * 256 + t;                          // < 1280
        int r = i / 160, e = i - r * 160;              // 160 float4 per row
        *(float4*)&s_w[r * KCH + e * 4] =
            *(const float4*)&Wsrc[(size_t)(lbase + r) * KF + (size_t)(k0 + e * 4)];
    }
    #pragma unroll
    for (int it = 0; it < 5; ++it){
        int i = it * 256 + t;
        int b = i / 160, e = i - b * 160;
        *(float4*)&s_f[b * KCH + e * 4] =
            *(const float4*)&f[(size_t)b * KF + (size_t)(k0 + e * 4)];
    }
    __syncthreads();

    // Compute: combo = t>>5 in [0,8): lq = combo>>2 (2 groups of 4 l-rows),
    // bq = combo&3 (4 groups of 2 b). ks = t&31 slices k.
    int combo = t >> 5, ks = t & 31;
    int l4 = (combo >> 2) * 4, b2 = (combo & 3) * 2;
    float acc[8];
    #pragma unroll
    for (int a = 0; a < 8; ++a) acc[a] = 0.f;

    #pragma unroll
    for (int sub = 0; sub < 5; ++sub){
        int e = sub * 32 + ks;                         // float4 idx in [0,160)
        const float4 w0 = *(const float4*)&s_w[(l4 + 0) * KCH + e * 4];
        const float4 w1 = *(const float4*)&s_w[(l4 + 1) * KCH + e * 4];
        const float4 w2 = *(const float4*)&s_w[(l4 + 2) * KCH + e * 4];
        const float4 w3 = *(const float4*)&s_w[(l4 + 3) * KCH + e * 4];
        const float4 fa = *(const float4*)&s_f[(b2 + 0) * KCH + e * 4];
        const float4 fb = *(const float4*)&s_f[(b2 + 1) * KCH + e * 4];
        acc[0] += w0.x*fa.x + w0.y*fa.y + w0.z*fa.z + w0.w*fa.w;
        acc[1] += w0.x*fb.x + w0.y*fb.y + w0.z*fb.z + w0.w*fb.w;
        acc[2] += w1.x*fa.x + w1.y*fa.y + w1.z*fa.z + w1.w*fa.w;
        acc[3] += w1.x*fb.x + w1.y*fb.y + w1.z*fb.z + w1.w*fb.w;
        acc[4] += w2.x*fa.x + w2.y*fa.y + w2.z*fa.z + w2.w*fa.w;
        acc[5] += w2.x*fb.x + w2.y*fb.y + w2.z*fb.z + w2.w*fb.w;
        acc[6] += w3.x*fa.x + w3.y*fa.y + w3.z*fa.z + w3.w*fa.w;
        acc[7] += w3.x*fb.x + w3.y*fb.y + w3.z*fb.z + w3.w*fb.w;
    }

    // Reduce over the 32-lane k-slice group (width=32 shuffles).
    #pragma unroll
    for (int a = 0; a < 8; ++a){
        float v = acc[a];
        v += __shfl_down(v, 16, 32); v += __shfl_down(v, 8, 32);
        v += __shfl_down(v, 4, 32);  v += __shfl_down(v, 2, 32);
        v += __shfl_down(v, 1, 32);
        acc[a] = v;
    }
    if (ks == 0){
        #pragma unroll
        for (int a = 0; a < 8; ++a){
            int l = a >> 1, b = a & 1;
            atomicAdd(&out[(b2 + b) * 512 + oofs + l4 + l], acc[a]);
        }
    }
}

// ---------------------------------------------------------------------------
extern "C" void kernel_launch(void* const* d_in, const int* in_sizes, int n_in,
                              void* d_out, int out_size, void* d_ws, size_t ws_size,
                              hipStream_t stream){
    const float* x            = (const float*)d_in[0];
    const int*   nb0          = (const int*)d_in[1];
    const int*   nb1          = (const int*)d_in[2];
    const int*   nb2          = (const int*)d_in[3];
    const int*   nb3          = (const int*)d_in[4];
    const float* weights0     = (const float*)d_in[5];
    const float* bias0        = (const float*)d_in[6];
    const float* w_weights0   = (const float*)d_in[7];
    const float* p_neighbors1 = (const float*)d_in[8];
    const float* weights2     = (const float*)d_in[9];
    const float* bias2        = (const float*)d_in[10];
    const float* w_weights2   = (const float*)d_in[11];
    const float* p_neighbors3 = (const float*)d_in[12];
    const float* W_miu        = (const float*)d_in[13];
    const float* b_miu        = (const float*)d_in[14];
    const float* W_sigma      = (const float*)d_in[15];
    const float* b_sigma      = (const float*)d_in[16];
    float* out = (float*)d_out;

    // ws layout (floats): h0 [0,10.24M) ; h1 [10.24M,12.8M) ; h2 reuses h0's
    // region [0,5.12M) after pool1 ; f [5.12M,6.4M) ; wT (bf16) at 12.8M.
    float* wsf = (float*)d_ws;
    float* h0 = wsf;
    float* h1 = wsf + 10240000;
    float* h2 = wsf;
    float* f  = wsf + 5120000;
    unsigned short* wT = (unsigned short*)(wsf + 12800000);

    k_wpack<<<288, 256, 0, stream>>>(weights2, wT);
    k_conv0<<<P0, 256, 0, stream>>>(x, nb0, weights0, bias0, w_weights0, h0);
    k_pool1<<<P1, 256, 0, stream>>>(h0, nb1, p_neighbors1, h1);
    k_conv2<<<P1 / 2, 256, 0, stream>>>(h1, nb2, w_weights2, bias2, wT, h2);
    k_pool3<<<P2, 256, 0, stream>>>(h2, nb3, p_neighbors3, f);
    k_init_out<<<16, 256, 0, stream>>>(b_miu, b_sigma, out);
    k_final<<<250 * 64, 256, 0, stream>>>(f, W_miu, W_sigma, out);
}